// Round 13
// baseline (134.562 us; speedup 1.0000x reference)
//
#include <hip/hip_runtime.h>
#include <hip/hip_bf16.h>

#define NNODES 16384

typedef unsigned short u16;
typedef unsigned int   u32;
typedef __attribute__((ext_vector_type(8))) short bf16x8;
typedef __attribute__((ext_vector_type(4))) float f32x4;

__device__ __forceinline__ float bfl(u32 u) { return __uint_as_float(u << 16); }
__device__ __forceinline__ float bfh(u32 u) { return __uint_as_float(u & 0xffff0000u); }
__device__ __forceinline__ u16 f2b(float f) {
    u32 u = __float_as_uint(f);
    return (u16)((u + 0x7fffu + ((u >> 16) & 1u)) >> 16);
}
__device__ __forceinline__ u32 pk2(float a, float b) {
    return (u32)f2b(a) | ((u32)f2b(b) << 16);
}
__device__ __forceinline__ bf16x8 bcast8(int4 v) {
    return __builtin_bit_cast(bf16x8, v);
}

#if defined(__has_builtin)
#if __has_builtin(__builtin_amdgcn_fdot2_f32_bf16)
#define HAVE_DOT2 1
#endif
#if __has_builtin(__builtin_amdgcn_sinf) && __has_builtin(__builtin_amdgcn_fractf)
#define HAVE_HWSIN 1
#endif
#endif
#ifndef HAVE_DOT2
#define HAVE_DOT2 0
#endif
#ifndef HAVE_HWSIN
#define HAVE_HWSIN 0
#endif

#if HAVE_DOT2
typedef __attribute__((ext_vector_type(2))) __bf16 bf16x2;
__device__ __forceinline__ float dot2b(u32 a, u32 b, float c) {
    return __builtin_amdgcn_fdot2_f32_bf16(__builtin_bit_cast(bf16x2, a),
                                           __builtin_bit_cast(bf16x2, b), c, false);
}
#else
__device__ __forceinline__ float dot2b(u32 a, u32 b, float c) {
    return c + bfl(a) * bfl(b) + bfh(a) * bfh(b);
}
#endif

#if HAVE_HWSIN
__device__ __forceinline__ float hwsin(float y) {
    return __builtin_amdgcn_sinf(__builtin_amdgcn_fractf(y));
}
#else
__device__ __forceinline__ float hwsin(float y) {
    return __sinf(y * 6.28318530717958647692f);
}
#endif

// ---------------------------------------------------------------------------
// setup_all: 99 blocks.
//  b in [0,96): weight cast+transpose (6 mats x 16 tiles) -> Wts bf16 [c][k]
//  b == 96:     qbias[c] = bq + btq + enc(t) @ Wtq[:,c]
//  b == 97:     Wtvp packing + wb2p table
//  b == 98:     Wtkb = bf16(Wtk)  ([64][128], row-major, no transpose)
// ---------------------------------------------------------------------------
__global__ __launch_bounds__(256) void setup_all(
    const float* __restrict__ Wk, const float* __restrict__ Wq,
    const float* __restrict__ Wv, const float* __restrict__ W1,
    const float* __restrict__ W2,
    const float* __restrict__ t,  const float* __restrict__ bq,
    const float* __restrict__ btq,const float* __restrict__ Wtq,
    const float* __restrict__ w0, const float* __restrict__ b0,
    const float* __restrict__ Wt, const float* __restrict__ Bt,
    const float* __restrict__ Wtk,const float* __restrict__ Wtv,
    u16* __restrict__ Wts, float* __restrict__ qbias,
    u32* __restrict__ Wtvp, float2* __restrict__ wb2p,
    u16* __restrict__ Wtkb)
{
    __shared__ float sb[192];
    int b = blockIdx.x, tt = threadIdx.x;

    if (b < 96) {
        int mat = b >> 4, tile = b & 15;
        const float* src = (mat == 0) ? Wk : (mat == 1) ? Wq : (mat == 2) ? Wv
                         : (mat == 3) ? W1 : (mat == 4) ? (W1 + 128 * 128) : W2;
        u16* dst = Wts + (size_t)mat * 16384;
        #pragma unroll
        for (int i = 0; i < 4; i++) {
            int o = i * 256 + tt;
            int cl = o >> 7, k = o & 127;
            int c = tile * 8 + cl;
            dst[c * 128 + k] = f2b(src[k * 128 + c]);
        }
    } else if (b == 96) {
        float tv = t[0];
        if (tt < 64)
            sb[tt] = (tt == 0) ? (w0[0] * tv + b0[0])
                               : __sinf(tv * Wt[tt - 1] + Bt[tt - 1]);
        __syncthreads();
        if (tt < 128) {
            float s = bq[tt] + btq[tt];
            for (int k = 0; k < 64; k++)
                s += sb[k] * Wtq[k * 128 + tt];
            qbias[tt] = s;
        }
    } else if (b == 97) {
        #pragma unroll
        for (int i = 0; i < 16; i++) {
            int idx = i * 256 + tt;
            int kp = idx >> 7, c = idx & 127;
            Wtvp[idx] = pk2(Wtv[(size_t)(2 * kp) * 128 + c],
                            Wtv[(size_t)(2 * kp + 1) * 128 + c]);
        }
        const float inv2pi = 0.15915494309189533577f;
        if (tt < 63) {
            float2 v;
            v.x = Wt[tt] * inv2pi;
            v.y = Bt[tt] * inv2pi;
            wb2p[tt + 1] = v;
        } else if (tt == 63) {
            float2 v;
            v.x = w0[0];
            v.y = b0[0];
            wb2p[0] = v;
        }
    } else {
        // Wtkb: [64][128] f32 -> bf16, same layout
        #pragma unroll
        for (int i = 0; i < 32; i++) {
            int idx = i * 256 + tt;
            Wtkb[idx] = f2b(Wtk[idx]);
        }
    }
}

// ---------------------------------------------------------------------------
// gemm4m2: fused 4-matrix MFMA GEMM over x, 2 mats per block.
// grid (NNODES/64, 2): grp 0 -> {Kb, Qb}; grp 1 -> {Vb, Pb}. All bf16 out.
// ---------------------------------------------------------------------------
__global__ __launch_bounds__(256) void gemm4m2(
    const float* __restrict__ x, const u16* __restrict__ Wts,
    const float* __restrict__ bk, const float* __restrict__ qbias,
    const float* __restrict__ bv, const float* __restrict__ b1,
    u16* __restrict__ Kb, u16* __restrict__ Qb,
    u16* __restrict__ Vb, u16* __restrict__ Pb)
{
    __shared__ u16 As[64 * 128];     // 16 KB
    __shared__ u16 Ws[128 * 128];    // 32 KB
    int t = threadIdx.x;
    int rb = blockIdx.x * 64;
    int grp = blockIdx.y;

    u32* As32 = (u32*)As;
    u32* Ws32 = (u32*)Ws;
    const float2* Ap = (const float2*)(x + (size_t)rb * 128);
    #pragma unroll
    for (int i = 0; i < 16; i++) {
        int idx2 = i * 256 + t;
        int r = idx2 >> 6, k2 = idx2 & 63;
        float2 v = Ap[idx2];
        As32[(r * 64 + k2) ^ ((r & 7) << 2)] = pk2(v.x, v.y);
    }

    int wid = t >> 6, lane = t & 63;
    int l15 = lane & 15, lg = lane >> 4;
    int mb = wid * 16;
    int xo = (l15 & 7) << 3;

    #pragma unroll
    for (int mi = 0; mi < 2; mi++) {
        int mat = grp * 2 + mi;
        const u16* Wt = Wts + (size_t)mat * 16384;
        const float* bias = (mat == 0) ? bk : (mat == 1) ? qbias
                          : (mat == 2) ? bv : b1;
        const u32* Wp = (const u32*)Wt;
        __syncthreads();
        #pragma unroll
        for (int i = 0; i < 32; i++) {
            int idx2 = i * 256 + t;
            int c = idx2 >> 6, k2 = idx2 & 63;
            Ws32[(c * 64 + k2) ^ ((c & 7) << 2)] = Wp[idx2];
        }
        __syncthreads();

        f32x4 acc[8];
        #pragma unroll
        for (int nt = 0; nt < 8; nt++) acc[nt] = (f32x4){0.f, 0.f, 0.f, 0.f};
        #pragma unroll
        for (int ks = 0; ks < 4; ks++) {
            int kq = ks * 32 + lg * 8;
            bf16x8 a0 = *(bf16x8*)&As[((mb + l15) * 128 + kq) ^ xo];
            #pragma unroll
            for (int nt = 0; nt < 8; nt++) {
                bf16x8 b = *(bf16x8*)&Ws[((nt * 16 + l15) * 128 + kq) ^ xo];
                acc[nt] = __builtin_amdgcn_mfma_f32_16x16x32_bf16(a0, b, acc[nt], 0, 0, 0);
            }
        }

        u16* dst = (mat == 0) ? Kb : (mat == 1) ? Qb : (mat == 2) ? Vb : Pb;
        #pragma unroll
        for (int nt = 0; nt < 8; nt++) {
            int c = nt * 16 + l15;
            float bvv = bias[c];
            #pragma unroll
            for (int j = 0; j < 4; j++) {
                size_t row = rb + mb + lg * 4 + j;
                dst[row * 128 + c] = f2b(acc[nt][j] + bvv);
            }
        }
    }
}

// ---------------------------------------------------------------------------
// mlp_fused: out = relu(Hb@W1b + Pb) @ W2 + b2, 32-row tiles. (unchanged)
// ---------------------------------------------------------------------------
__global__ __launch_bounds__(256) void mlp_fused(
    const u16* __restrict__ Hb, const u16* __restrict__ Wts,
    const u16* __restrict__ Pb, const float* __restrict__ b2,
    float* __restrict__ out)
{
    __shared__ u16 As[32 * 128];     //  8 KB
    __shared__ u16 Ws[128 * 128];    // 32 KB
    int t = threadIdx.x;
    int rb = blockIdx.x * 32;
    u32* As32 = (u32*)As;
    u32* Ws32 = (u32*)Ws;

    const u32* Hp = (const u32*)(Hb + (size_t)rb * 128);
    #pragma unroll
    for (int i = 0; i < 8; i++) {
        int idx2 = i * 256 + t;
        int r = idx2 >> 6, k2 = idx2 & 63;
        As32[(r * 64 + k2) ^ ((r & 7) << 2)] = Hp[idx2];
    }
    {
        const u32* Wp = (const u32*)(Wts + 4 * 16384);
        #pragma unroll
        for (int i = 0; i < 32; i++) {
            int idx2 = i * 256 + t;
            int c = idx2 >> 6, k2 = idx2 & 63;
            Ws32[(c * 64 + k2) ^ ((c & 7) << 2)] = Wp[idx2];
        }
    }
    __syncthreads();

    int wid = t >> 6, lane = t & 63;
    int l15 = lane & 15, lg = lane >> 4;
    int rh = wid >> 1, ch = wid & 1;
    int mb = rh * 16;
    int xo = (l15 & 7) << 3;

    f32x4 acc[4];
    #pragma unroll
    for (int nt = 0; nt < 4; nt++) acc[nt] = (f32x4){0.f, 0.f, 0.f, 0.f};
    #pragma unroll
    for (int ks = 0; ks < 4; ks++) {
        int kq = ks * 32 + lg * 8;
        bf16x8 a0 = *(bf16x8*)&As[((mb + l15) * 128 + kq) ^ xo];
        #pragma unroll
        for (int nt = 0; nt < 4; nt++) {
            bf16x8 b = *(bf16x8*)&Ws[(((ch * 4 + nt) * 16 + l15) * 128 + kq) ^ xo];
            acc[nt] = __builtin_amdgcn_mfma_f32_16x16x32_bf16(a0, b, acc[nt], 0, 0, 0);
        }
    }
    __syncthreads();

    #pragma unroll
    for (int nt = 0; nt < 4; nt++) {
        int c = ch * 64 + nt * 16 + l15;
        #pragma unroll
        for (int j = 0; j < 4; j++) {
            int row = mb + lg * 4 + j;
            float pv = bfl((u32)Pb[(size_t)(rb + row) * 128 + c]);
            float v = fmaxf(acc[nt][j] + pv, 0.f);
            As[(row * 128 + c) ^ ((row & 7) << 3)] = f2b(v);
        }
    }
    {
        const u32* Wp = (const u32*)(Wts + 5 * 16384);
        #pragma unroll
        for (int i = 0; i < 32; i++) {
            int idx2 = i * 256 + t;
            int c = idx2 >> 6, k2 = idx2 & 63;
            Ws32[(c * 64 + k2) ^ ((c & 7) << 2)] = Wp[idx2];
        }
    }
    __syncthreads();

    #pragma unroll
    for (int nt = 0; nt < 4; nt++) acc[nt] = (f32x4){0.f, 0.f, 0.f, 0.f};
    #pragma unroll
    for (int ks = 0; ks < 4; ks++) {
        int kq = ks * 32 + lg * 8;
        bf16x8 a0 = *(bf16x8*)&As[((mb + l15) * 128 + kq) ^ xo];
        #pragma unroll
        for (int nt = 0; nt < 4; nt++) {
            bf16x8 b = *(bf16x8*)&Ws[(((ch * 4 + nt) * 16 + l15) * 128 + kq) ^ xo];
            acc[nt] = __builtin_amdgcn_mfma_f32_16x16x32_bf16(a0, b, acc[nt], 0, 0, 0);
        }
    }
    #pragma unroll
    for (int nt = 0; nt < 4; nt++) {
        int c = ch * 64 + nt * 16 + l15;
        float bvv = b2[c];
        #pragma unroll
        for (int j = 0; j < 4; j++) {
            size_t row = rb + mb + lg * 4 + j;
            out[row * 128 + c] = acc[nt][j] + bvv;
        }
    }
}

// ---------------------------------------------------------------------------
// Attention: R8/R12 structure; change: G computed in-wave via 16 MFMAs from
// the L2-resident Wtkb table (kills the 16 MB Gb stream). G-MFMA reuses the
// QK loop's block-diagonal qf fragments; C-layout (col=l15, row=4*lg+j)
// packs straight into the existing gbp layout. One wave per node, 4 waves
// per block, wave-private LDS, no barriers.
// ---------------------------------------------------------------------------
__global__ __launch_bounds__(256, 5) void attn_kernel(
    const int*   __restrict__ neighbors, const float* __restrict__ times,
    const float* __restrict__ tptr,
    const u16* __restrict__ Kb, const u16* __restrict__ Qb,
    const u16* __restrict__ Vb, const u16* __restrict__ Wtkb,
    const float* __restrict__ btk,  const u32* __restrict__ Wtvp,
    const float* __restrict__ btv,
    const float2* __restrict__ wb2p,
    u16* __restrict__ Hb)
{
    __shared__ u16   enc[4][32][72];
    __shared__ u32   gbp[4][8][32];
    __shared__ u32   qb[4][64];
    __shared__ float pbuf[4][8][33];
    __shared__ u16   ewp[4][8][66];
    __shared__ int   nbb[4][32];
    __shared__ float cb_[4][8];

    int t = threadIdx.x;
    int wid = t >> 6, lane = t & 63;
    int n = blockIdx.x * 4 + wid;
    float t0 = tptr[0];
    int l15 = lane & 15, lg = lane >> 4;

    qb[wid][lane] = ((const u32*)Qb)[(size_t)n * 64 + lane];

    int m = lane & 31, h2 = lane >> 5;
    if (lane < 32) nbb[wid][lane] = neighbors[n * 32 + lane];
    float tm = times[n * 32 + m];
    bool valid = (tm <= t0);
    unsigned long long bal = __ballot(valid);
    bool anyv = (bal != 0ull);

    // ---- V preload (issue before G compute; gathers fly under MFMAs) ----
    u32 vpre[32];
    #pragma unroll
    for (int mm = 0; mm < 32; mm++) {
        int nbm = nbb[wid][mm];
        vpre[mm] = *(const u32*)(Vb + (size_t)nbm * 128 + 2 * lane);
    }

    const int4 zero4 = {0, 0, 0, 0};

    // ================= G = Wtk @ Qexp via MFMA (16 MFMAs) =================
    // G[j][h] = sum_d Wtk[j][h*16+d] * q[h*16+d]; A = Wtkb rows, B = Qexp.
    {
        f32x4 gacc[4];
        #pragma unroll
        for (int mt = 0; mt < 4; mt++) gacc[mt] = (f32x4){0.f, 0.f, 0.f, 0.f};
        #pragma unroll
        for (int ks = 0; ks < 4; ks++) {
            bf16x8 qf = bcast8((l15 == ks * 2 + (lg >> 1))
                                   ? *(const int4*)&qb[wid][ks * 16 + lg * 4]
                                   : zero4);
            #pragma unroll
            for (int mt = 0; mt < 4; mt++) {
                bf16x8 af = bcast8(*(const int4*)(Wtkb + (size_t)(mt * 16 + l15) * 128
                                                  + ks * 32 + lg * 8));
                gacc[mt] = __builtin_amdgcn_mfma_f32_16x16x32_bf16(af, qf, gacc[mt], 0, 0, 0);
            }
        }
        // C-layout: lane (l15, lg) holds G[mt*16 + lg*4 + j][l15]; pack pairs.
        if (l15 < 8) {
            #pragma unroll
            for (int mt = 0; mt < 4; mt++) {
                gbp[wid][l15][mt * 8 + lg * 2]     = pk2(gacc[mt][0], gacc[mt][1]);
                gbp[wid][l15][mt * 8 + lg * 2 + 1] = pk2(gacc[mt][2], gacc[mt][3]);
            }
        }
    }

    // ---- time encoding (hw-sin) ----
    int kbase = 32 * h2;
    #pragma unroll
    for (int i = 0; i < 16; i++) {
        int k0 = kbase + 2 * i;
        float2 wbA = wb2p[k0];
        float2 wbB = wb2p[k0 + 1];
        float yA = fmaf(tm, wbA.x, wbA.y);
        float yB = fmaf(tm, wbB.x, wbB.y);
        float v0 = (k0 == 0) ? yA : hwsin(yA);
        float v1 = hwsin(yB);
        *(u32*)&enc[wid][m][k0] = pk2(v0, v1);
    }

    // cb_[h] = q_h . btk_h
    if (lane < 8) {
        float s = 0.f;
        #pragma unroll
        for (int j = 0; j < 8; j++) {
            u32 qp = qb[wid][lane * 8 + j];
            s += bfl(qp) * btk[lane * 16 + 2 * j] + bfh(qp) * btk[lane * 16 + 2 * j + 1];
        }
        cb_[wid][lane] = s;
    }

    // ================= scores via MFMA =================
    f32x4 accS[2];
    accS[0] = (f32x4){0.f, 0.f, 0.f, 0.f};
    accS[1] = (f32x4){0.f, 0.f, 0.f, 0.f};

    int nb0 = nbb[wid][l15];
    int nb1 = nbb[wid][l15 + 16];
    const u16* K0 = Kb + (size_t)nb0 * 128;
    const u16* K1 = Kb + (size_t)nb1 * 128;
    #pragma unroll
    for (int ks = 0; ks < 4; ks++) {
        bf16x8 qf = bcast8((l15 == ks * 2 + (lg >> 1))
                               ? *(const int4*)&qb[wid][ks * 16 + lg * 4]
                               : zero4);
        bf16x8 k0f = bcast8(*(const int4*)(K0 + ks * 32 + lg * 8));
        bf16x8 k1f = bcast8(*(const int4*)(K1 + ks * 32 + lg * 8));
        accS[0] = __builtin_amdgcn_mfma_f32_16x16x32_bf16(k0f, qf, accS[0], 0, 0, 0);
        accS[1] = __builtin_amdgcn_mfma_f32_16x16x32_bf16(k1f, qf, accS[1], 0, 0, 0);
    }
    #pragma unroll
    for (int ks = 0; ks < 2; ks++) {
        int4 gi = zero4;
        if (l15 < 8) {
            int2 ga = *(const int2*)&gbp[wid][l15][ks * 16 + lg * 4];
            int2 gbq = *(const int2*)&gbp[wid][l15][ks * 16 + lg * 4 + 2];
            gi.x = ga.x; gi.y = ga.y; gi.z = gbq.x; gi.w = gbq.y;
        }
        bf16x8 gf = bcast8(gi);
        bf16x8 e0 = *(const bf16x8*)&enc[wid][l15][ks * 32 + lg * 8];
        bf16x8 e1 = *(const bf16x8*)&enc[wid][l15 + 16][ks * 32 + lg * 8];
        accS[0] = __builtin_amdgcn_mfma_f32_16x16x32_bf16(e0, gf, accS[0], 0, 0, 0);
        accS[1] = __builtin_amdgcn_mfma_f32_16x16x32_bf16(e1, gf, accS[1], 0, 0, 0);
    }

    // ---- finalize + softmax (mask from ballot) ----
    float cbv = (l15 < 8) ? cb_[wid][l15] : 0.f;
    float sc[2][4];
    #pragma unroll
    for (int mt = 0; mt < 2; mt++) {
        #pragma unroll
        for (int j = 0; j < 4; j++) {
            int mr = mt * 16 + lg * 4 + j;
            float v = 0.25f * (accS[mt][j] + cbv);
            sc[mt][j] = ((bal >> mr) & 1ull) ? v : -1e9f;
        }
    }
    float mx = sc[0][0];
    #pragma unroll
    for (int mt = 0; mt < 2; mt++)
        #pragma unroll
        for (int j = 0; j < 4; j++) mx = fmaxf(mx, sc[mt][j]);
    mx = fmaxf(mx, __shfl_xor(mx, 16));
    mx = fmaxf(mx, __shfl_xor(mx, 32));
    float p[2][4];
    float s = 0.f;
    #pragma unroll
    for (int mt = 0; mt < 2; mt++)
        #pragma unroll
        for (int j = 0; j < 4; j++) { p[mt][j] = __expf(sc[mt][j] - mx); s += p[mt][j]; }
    s += __shfl_xor(s, 16);
    s += __shfl_xor(s, 32);
    float inv = 1.0f / s;
    if (l15 < 8) {
        #pragma unroll
        for (int mt = 0; mt < 2; mt++)
            #pragma unroll
            for (int j = 0; j < 4; j++)
                pbuf[wid][l15][mt * 16 + lg * 4 + j] = p[mt][j] * inv;
    }

    // ================= ewp = P^T @ enc via MFMA =================
    {
        int hh = l15 & 7;
        float pa[8];
        #pragma unroll
        for (int j = 0; j < 8; j++) pa[j] = pbuf[wid][hh][8 * lg + j];
        int4 ai;
        ai.x = pk2(pa[0], pa[1]); ai.y = pk2(pa[2], pa[3]);
        ai.z = pk2(pa[4], pa[5]); ai.w = pk2(pa[6], pa[7]);
        bf16x8 af = bcast8(ai);
        #pragma unroll
        for (int nt = 0; nt < 4; nt++) {
            int col = nt * 16 + l15;
            int4 bi;
            bi.x = (u32)enc[wid][8 * lg + 0][col] | ((u32)enc[wid][8 * lg + 1][col] << 16);
            bi.y = (u32)enc[wid][8 * lg + 2][col] | ((u32)enc[wid][8 * lg + 3][col] << 16);
            bi.z = (u32)enc[wid][8 * lg + 4][col] | ((u32)enc[wid][8 * lg + 5][col] << 16);
            bi.w = (u32)enc[wid][8 * lg + 6][col] | ((u32)enc[wid][8 * lg + 7][col] << 16);
            bf16x8 bfr = bcast8(bi);
            f32x4 ce = (f32x4){0.f, 0.f, 0.f, 0.f};
            ce = __builtin_amdgcn_mfma_f32_16x16x32_bf16(af, bfr, ce, 0, 0, 0);
            if (lg < 2) {
                #pragma unroll
                for (int j = 0; j < 4; j++)
                    ewp[wid][4 * lg + j][col] = f2b(ce[j]);
            }
        }
    }

    // ---- V aggregation (VALU) ----
    int myh = lane >> 3;
    float av0 = 0.f, av1 = 0.f;
    #pragma unroll
    for (int mm = 0; mm < 32; mm++) {
        float a = pbuf[wid][myh][mm];
        av0 += a * bfl(vpre[mm]);
        av1 += a * bfh(vpre[mm]);
    }
    // ---- time-value term ----
    float ht0 = 0.f, ht1 = 0.f;
    #pragma unroll 8
    for (int kp = 0; kp < 32; kp++) {
        u32 ew = *(const u32*)&ewp[wid][myh][2 * kp];
        int2 wv = *(const int2*)&Wtvp[kp * 128 + 2 * lane];
        ht0 = dot2b(ew, (u32)wv.x, ht0);
        ht1 = dot2b(ew, (u32)wv.y, ht1);
    }
    float2 bt2 = *(const float2*)&btv[2 * lane];
    float ox = anyv ? (av0 + ht0 + bt2.x) : 0.0f;
    float oy = anyv ? (av1 + ht1 + bt2.y) : 0.0f;
    ((u32*)Hb)[(size_t)n * 64 + lane] = pk2(ox, oy);
}

// ---------------------------------------------------------------------------
extern "C" void kernel_launch(void* const* d_in, const int* in_sizes, int n_in,
                              void* d_out, int out_size, void* d_ws, size_t ws_size,
                              hipStream_t stream)
{
    const float* x        = (const float*)d_in[0];
    const int*   neighbors= (const int*)  d_in[1];
    const float* times    = (const float*)d_in[2];
    const float* t        = (const float*)d_in[3];
    const float* Wk  = (const float*)d_in[4];
    const float* bk  = (const float*)d_in[5];
    const float* Wq  = (const float*)d_in[6];
    const float* bq  = (const float*)d_in[7];
    const float* Wv  = (const float*)d_in[8];
    const float* bv  = (const float*)d_in[9];
    const float* w0  = (const float*)d_in[10];
    const float* b0  = (const float*)d_in[11];
    const float* Wt  = (const float*)d_in[12];
    const float* Bt  = (const float*)d_in[13];
    const float* Wtk = (const float*)d_in[14];
    const float* btk = (const float*)d_in[15];
    const float* Wtq = (const float*)d_in[16];
    const float* btq = (const float*)d_in[17];
    const float* Wtv = (const float*)d_in[18];
    const float* btv = (const float*)d_in[19];
    const float* W1  = (const float*)d_in[20];
    const float* b1  = (const float*)d_in[21];
    const float* W2  = (const float*)d_in[22];
    const float* b2  = (const float*)d_in[23];

    float* ws = (float*)d_ws;
    const size_t NF = (size_t)NNODES * 128;
    u16*   Kb    = (u16*)ws;                             // NF bf16
    u16*   Qb    = Kb + NF;                              // NF bf16
    u16*   Vb    = Qb + NF;                              // NF bf16
    u16*   Pb    = Vb + NF;                              // NF bf16
    u16*   Hb    = Pb + NF;                              // NF bf16
    float* qbias = (float*)(Hb + NF);                    // 128 f32
    u16*   Wts   = (u16*)(qbias + 128);                  // 6*16384 bf16
    u32*   Wtvp  = (u32*)(Wts + 6 * 16384);              // 4096 u32
    float2* wb2p = (float2*)(Wtvp + 4096);               // 64 float2
    u16*   Wtkb  = (u16*)(wb2p + 64);                    // 8192 bf16

    setup_all<<<99, 256, 0, stream>>>(Wk, Wq, Wv, W1, W2,
                                      t, bq, btq, Wtq, w0, b0, Wt, Bt,
                                      Wtk, Wtv,
                                      Wts, qbias, Wtvp, wb2p, Wtkb);

    gemm4m2<<<dim3(NNODES / 64, 2), 256, 0, stream>>>(
        x, Wts, bk, qbias, bv, b1, Kb, Qb, Vb, Pb);

    attn_kernel<<<NNODES / 4, 256, 0, stream>>>(neighbors, times, t,
                                                Kb, Qb, Vb, Wtkb,
                                                btk, Wtvp, btv, wb2p,
                                                Hb);

    mlp_fused<<<NNODES / 32, 256, 0, stream>>>(Hb, Wts, Pb, b2,
                                               (float*)d_out);
}

// Round 14
// 101.041 us; speedup vs baseline: 1.3318x; 1.3318x over previous
//
#include <hip/hip_runtime.h>
#include <hip/hip_bf16.h>

#define NNODES 16384

typedef unsigned short u16;
typedef unsigned int   u32;
typedef __attribute__((ext_vector_type(8))) short bf16x8;
typedef __attribute__((ext_vector_type(4))) float f32x4;

__device__ __forceinline__ float bfl(u32 u) { return __uint_as_float(u << 16); }
__device__ __forceinline__ float bfh(u32 u) { return __uint_as_float(u & 0xffff0000u); }
__device__ __forceinline__ u16 f2b(float f) {
    u32 u = __float_as_uint(f);
    return (u16)((u + 0x7fffu + ((u >> 16) & 1u)) >> 16);
}
__device__ __forceinline__ u32 pk2(float a, float b) {
    return (u32)f2b(a) | ((u32)f2b(b) << 16);
}
__device__ __forceinline__ bf16x8 bcast8(int4 v) {
    return __builtin_bit_cast(bf16x8, v);
}

#if defined(__has_builtin)
#if __has_builtin(__builtin_amdgcn_fdot2_f32_bf16)
#define HAVE_DOT2 1
#endif
#if __has_builtin(__builtin_amdgcn_sinf) && __has_builtin(__builtin_amdgcn_fractf)
#define HAVE_HWSIN 1
#endif
#endif
#ifndef HAVE_DOT2
#define HAVE_DOT2 0
#endif
#ifndef HAVE_HWSIN
#define HAVE_HWSIN 0
#endif

#if HAVE_DOT2
typedef __attribute__((ext_vector_type(2))) __bf16 bf16x2;
__device__ __forceinline__ float dot2b(u32 a, u32 b, float c) {
    return __builtin_amdgcn_fdot2_f32_bf16(__builtin_bit_cast(bf16x2, a),
                                           __builtin_bit_cast(bf16x2, b), c, false);
}
#else
__device__ __forceinline__ float dot2b(u32 a, u32 b, float c) {
    return c + bfl(a) * bfl(b) + bfh(a) * bfh(b);
}
#endif

// hwsin: y in revolutions (already divided by 2*pi)
#if HAVE_HWSIN
__device__ __forceinline__ float hwsin(float y) {
    return __builtin_amdgcn_sinf(__builtin_amdgcn_fractf(y));
}
#else
__device__ __forceinline__ float hwsin(float y) {
    return __sinf(y * 6.28318530717958647692f);
}
#endif

// ---------------------------------------------------------------------------
// setup_all: one wide kernel, 107 blocks. (R11 + wb2p table in block 98)
// wb2p[0] = (w0, b0) raw; wb2p[k] = (Wt[k-1], Bt[k-1]) / 2pi  for k=1..63
// ---------------------------------------------------------------------------
__global__ __launch_bounds__(256) void setup_all(
    const float* __restrict__ Wk, const float* __restrict__ Wq,
    const float* __restrict__ Wv, const float* __restrict__ W1,
    const float* __restrict__ W2,
    const float* __restrict__ t,  const float* __restrict__ bq,
    const float* __restrict__ btq,const float* __restrict__ Wtq,
    const float* __restrict__ w0, const float* __restrict__ b0,
    const float* __restrict__ Wt, const float* __restrict__ Bt,
    const float* __restrict__ Wtk,const float* __restrict__ Wtv,
    u16* __restrict__ Wts, float* __restrict__ qbias,
    float* __restrict__ gb, u32* __restrict__ Wtvp, u16* __restrict__ WGt,
    float2* __restrict__ wb2p)
{
    __shared__ float sb[128 * 17 + 64 * 17];
    int b = blockIdx.x, tt = threadIdx.x;

    if (b < 96) {
        int mat = b >> 4, tile = b & 15;
        const float* src = (mat == 0) ? Wk : (mat == 1) ? Wq : (mat == 2) ? Wv
                         : (mat == 3) ? W1 : (mat == 4) ? (W1 + 128 * 128) : W2;
        u16* dst = Wts + (size_t)mat * 16384;
        #pragma unroll
        for (int i = 0; i < 4; i++) {
            int o = i * 256 + tt;
            int cl = o >> 7, k = o & 127;
            int c = tile * 8 + cl;
            dst[c * 128 + k] = f2b(src[k * 128 + c]);
        }
    } else if (b == 96 || b == 97) {
        float tv = t[0];
        if (tt < 64)
            sb[tt] = (tt == 0) ? (w0[0] * tv + b0[0])
                               : __sinf(tv * Wt[tt - 1] + Bt[tt - 1]);
        __syncthreads();
        if (tt < 128) {
            float s = bq[tt] + btq[tt];
            for (int k = 0; k < 64; k++)
                s += sb[k] * Wtq[k * 128 + tt];
            sb[64 + tt] = s;
            if (b == 96) qbias[tt] = s;
        }
        __syncthreads();
        if (b == 97) {
            #pragma unroll
            for (int r = 0; r < 2; r++) {
                int hj = tt + r * 256;
                int h = hj >> 6, j = hj & 63;
                float s = 0.f;
                #pragma unroll
                for (int d = 0; d < 16; d++)
                    s += sb[64 + h * 16 + d] * Wtk[(size_t)j * 128 + h * 16 + d];
                gb[hj] = s;
            }
        }
    } else if (b == 98) {
        #pragma unroll
        for (int i = 0; i < 16; i++) {
            int idx = i * 256 + tt;
            int kp = idx >> 7, c = idx & 127;
            Wtvp[idx] = pk2(Wtv[(size_t)(2 * kp) * 128 + c],
                            Wtv[(size_t)(2 * kp + 1) * 128 + c]);
        }
        const float inv2pi = 0.15915494309189533577f;
        if (tt < 63) {
            float2 v;
            v.x = Wt[tt] * inv2pi;
            v.y = Bt[tt] * inv2pi;
            wb2p[tt + 1] = v;
        } else if (tt == 63) {
            float2 v;
            v.x = w0[0];
            v.y = b0[0];
            wb2p[0] = v;
        }
    } else {
        int h = b - 99;
        float* WqL  = sb;
        float* WtkL = sb + 128 * 17;
        #pragma unroll
        for (int i = 0; i < 8; i++) {
            int o = i * 256 + tt;
            int k = o >> 4, d = o & 15;
            WqL[k * 17 + d] = Wq[(size_t)k * 128 + h * 16 + d];
        }
        #pragma unroll
        for (int i = 0; i < 4; i++) {
            int o = i * 256 + tt;
            int j = o >> 4, d = o & 15;
            WtkL[j * 17 + d] = Wtk[(size_t)j * 128 + h * 16 + d];
        }
        __syncthreads();
        int j = tt >> 2, kb = (tt & 3) * 32;
        float wk[16];
        #pragma unroll
        for (int d = 0; d < 16; d++) wk[d] = WtkL[j * 17 + d];
        u32 out[16];
        #pragma unroll
        for (int kk2 = 0; kk2 < 16; kk2++) {
            int k = kb + 2 * kk2;
            float s0 = 0.f, s1 = 0.f;
            #pragma unroll
            for (int d = 0; d < 16; d++) {
                s0 += WqL[k * 17 + d] * wk[d];
                s1 += WqL[(k + 1) * 17 + d] * wk[d];
            }
            out[kk2] = pk2(s0, s1);
        }
        int4* dst = (int4*)(WGt + (size_t)(h * 64 + j) * 128 + kb);
        const int4* srcv = (const int4*)out;
        #pragma unroll
        for (int i = 0; i < 4; i++) dst[i] = srcv[i];
    }
}

// ---------------------------------------------------------------------------
// gemm8m4: fused 8-matrix MFMA GEMM over x, 4 mats per block. (unchanged)
// ---------------------------------------------------------------------------
__global__ __launch_bounds__(256) void gemm8m4(
    const float* __restrict__ x, const u16* __restrict__ Wts,
    const u16* __restrict__ WGt,
    const float* __restrict__ bk, const float* __restrict__ qbias,
    const float* __restrict__ bv, const float* __restrict__ b1,
    const float* __restrict__ gb,
    u16* __restrict__ Kb, u16* __restrict__ Qb,
    u16* __restrict__ Vb, u16* __restrict__ Pb, u16* __restrict__ Gb)
{
    __shared__ u16 As[64 * 128];     // 16 KB
    __shared__ u16 Ws[128 * 128];    // 32 KB
    int t = threadIdx.x;
    int rb = blockIdx.x * 64;
    int grp = blockIdx.y;

    u32* As32 = (u32*)As;
    u32* Ws32 = (u32*)Ws;
    const float2* Ap = (const float2*)(x + (size_t)rb * 128);
    #pragma unroll
    for (int i = 0; i < 16; i++) {
        int idx2 = i * 256 + t;
        int r = idx2 >> 6, k2 = idx2 & 63;
        float2 v = Ap[idx2];
        As32[(r * 64 + k2) ^ ((r & 7) << 2)] = pk2(v.x, v.y);
    }

    int wid = t >> 6, lane = t & 63;
    int l15 = lane & 15, lg = lane >> 4;
    int mb = wid * 16;
    int xo = (l15 & 7) << 3;

    #pragma unroll
    for (int mi = 0; mi < 4; mi++) {
        int mat = grp * 4 + mi;
        const u16* Wt = (mat < 4) ? (Wts + (size_t)mat * 16384)
                                  : (WGt + (size_t)(mat - 4) * 16384);
        const float* bias = (mat == 0) ? bk : (mat == 1) ? qbias
                          : (mat == 2) ? bv : (mat == 3) ? b1
                          : (gb + (mat - 4) * 128);
        const u32* Wp = (const u32*)Wt;
        __syncthreads();
        #pragma unroll
        for (int i = 0; i < 32; i++) {
            int idx2 = i * 256 + t;
            int c = idx2 >> 6, k2 = idx2 & 63;
            Ws32[(c * 64 + k2) ^ ((c & 7) << 2)] = Wp[idx2];
        }
        __syncthreads();

        f32x4 acc[8];
        #pragma unroll
        for (int nt = 0; nt < 8; nt++) acc[nt] = (f32x4){0.f, 0.f, 0.f, 0.f};
        #pragma unroll
        for (int ks = 0; ks < 4; ks++) {
            int kq = ks * 32 + lg * 8;
            bf16x8 a0 = *(bf16x8*)&As[((mb + l15) * 128 + kq) ^ xo];
            #pragma unroll
            for (int nt = 0; nt < 8; nt++) {
                bf16x8 b = *(bf16x8*)&Ws[((nt * 16 + l15) * 128 + kq) ^ xo];
                acc[nt] = __builtin_amdgcn_mfma_f32_16x16x32_bf16(a0, b, acc[nt], 0, 0, 0);
            }
        }

        u16* dst = (mat == 0) ? Kb : (mat == 1) ? Qb : (mat == 2) ? Vb
                 : (mat == 3) ? Pb : Gb;
        #pragma unroll
        for (int nt = 0; nt < 8; nt++) {
            int c = nt * 16 + l15;
            float bvv = bias[c];
            #pragma unroll
            for (int j = 0; j < 4; j++) {
                size_t row = rb + mb + lg * 4 + j;
                float v = acc[nt][j] + bvv;
                if (mat < 4) dst[row * 128 + c] = f2b(v);
                else         dst[row * 512 + (size_t)(mat - 4) * 128 + c] = f2b(v);
            }
        }
    }
}

// ---------------------------------------------------------------------------
// mlp_fused: out = relu(Hb@W1b + Pb) @ W2 + b2, 32-row tiles. (unchanged)
// ---------------------------------------------------------------------------
__global__ __launch_bounds__(256) void mlp_fused(
    const u16* __restrict__ Hb, const u16* __restrict__ Wts,
    const u16* __restrict__ Pb, const float* __restrict__ b2,
    float* __restrict__ out)
{
    __shared__ u16 As[32 * 128];     //  8 KB
    __shared__ u16 Ws[128 * 128];    // 32 KB
    int t = threadIdx.x;
    int rb = blockIdx.x * 32;
    u32* As32 = (u32*)As;
    u32* Ws32 = (u32*)Ws;

    const u32* Hp = (const u32*)(Hb + (size_t)rb * 128);
    #pragma unroll
    for (int i = 0; i < 8; i++) {
        int idx2 = i * 256 + t;
        int r = idx2 >> 6, k2 = idx2 & 63;
        As32[(r * 64 + k2) ^ ((r & 7) << 2)] = Hp[idx2];
    }
    {
        const u32* Wp = (const u32*)(Wts + 4 * 16384);
        #pragma unroll
        for (int i = 0; i < 32; i++) {
            int idx2 = i * 256 + t;
            int c = idx2 >> 6, k2 = idx2 & 63;
            Ws32[(c * 64 + k2) ^ ((c & 7) << 2)] = Wp[idx2];
        }
    }
    __syncthreads();

    int wid = t >> 6, lane = t & 63;
    int l15 = lane & 15, lg = lane >> 4;
    int rh = wid >> 1, ch = wid & 1;
    int mb = rh * 16;
    int xo = (l15 & 7) << 3;

    f32x4 acc[4];
    #pragma unroll
    for (int nt = 0; nt < 4; nt++) acc[nt] = (f32x4){0.f, 0.f, 0.f, 0.f};
    #pragma unroll
    for (int ks = 0; ks < 4; ks++) {
        int kq = ks * 32 + lg * 8;
        bf16x8 a0 = *(bf16x8*)&As[((mb + l15) * 128 + kq) ^ xo];
        #pragma unroll
        for (int nt = 0; nt < 4; nt++) {
            bf16x8 b = *(bf16x8*)&Ws[(((ch * 4 + nt) * 16 + l15) * 128 + kq) ^ xo];
            acc[nt] = __builtin_amdgcn_mfma_f32_16x16x32_bf16(a0, b, acc[nt], 0, 0, 0);
        }
    }
    __syncthreads();

    #pragma unroll
    for (int nt = 0; nt < 4; nt++) {
        int c = ch * 64 + nt * 16 + l15;
        #pragma unroll
        for (int j = 0; j < 4; j++) {
            int row = mb + lg * 4 + j;
            float pv = bfl((u32)Pb[(size_t)(rb + row) * 128 + c]);
            float v = fmaxf(acc[nt][j] + pv, 0.f);
            As[(row * 128 + c) ^ ((row & 7) << 3)] = f2b(v);
        }
    }
    {
        const u32* Wp = (const u32*)(Wts + 5 * 16384);
        #pragma unroll
        for (int i = 0; i < 32; i++) {
            int idx2 = i * 256 + t;
            int c = idx2 >> 6, k2 = idx2 & 63;
            Ws32[(c * 64 + k2) ^ ((c & 7) << 2)] = Wp[idx2];
        }
    }
    __syncthreads();

    #pragma unroll
    for (int nt = 0; nt < 4; nt++) acc[nt] = (f32x4){0.f, 0.f, 0.f, 0.f};
    #pragma unroll
    for (int ks = 0; ks < 4; ks++) {
        int kq = ks * 32 + lg * 8;
        bf16x8 a0 = *(bf16x8*)&As[((mb + l15) * 128 + kq) ^ xo];
        #pragma unroll
        for (int nt = 0; nt < 4; nt++) {
            bf16x8 b = *(bf16x8*)&Ws[(((ch * 4 + nt) * 16 + l15) * 128 + kq) ^ xo];
            acc[nt] = __builtin_amdgcn_mfma_f32_16x16x32_bf16(a0, b, acc[nt], 0, 0, 0);
        }
    }
    #pragma unroll
    for (int nt = 0; nt < 4; nt++) {
        int c = ch * 64 + nt * 16 + l15;
        float bvv = b2[c];
        #pragma unroll
        for (int j = 0; j < 4; j++) {
            size_t row = rb + mb + lg * 4 + j;
            out[row * 128 + c] = acc[nt][j] + bvv;
        }
    }
}

// ---------------------------------------------------------------------------
// Attention (R8/R11 structure; hw-sin enc via wb2p tables). Best measured:
// 57.7 us. One wave per node, 4 waves/block, wave-private LDS, no barriers.
// ---------------------------------------------------------------------------
__global__ __launch_bounds__(256, 5) void attn_kernel(
    const int*   __restrict__ neighbors, const float* __restrict__ times,
    const float* __restrict__ tptr,
    const u16* __restrict__ Kb, const u16* __restrict__ Qb,
    const u16* __restrict__ Vb, const u16* __restrict__ Gb,
    const float* __restrict__ btk,  const u32* __restrict__ Wtvp,
    const float* __restrict__ btv,
    const float2* __restrict__ wb2p,
    u16* __restrict__ Hb)
{
    __shared__ u16   enc[4][32][72];
    __shared__ u32   gbp[4][8][32];
    __shared__ u32   qb[4][64];
    __shared__ float pbuf[4][8][33];
    __shared__ u16   ewp[4][8][66];
    __shared__ int   nbb[4][32];
    __shared__ float cb_[4][8];

    int t = threadIdx.x;
    int wid = t >> 6, lane = t & 63;
    int n = blockIdx.x * 4 + wid;
    float t0 = tptr[0];
    int l15 = lane & 15, lg = lane >> 4;

    qb[wid][lane] = ((const u32*)Qb)[(size_t)n * 64 + lane];
    {
        int4 g4 = *(const int4*)((const u32*)Gb + (size_t)n * 256 + 4 * lane);
        const u32* gw = (const u32*)&g4;
        #pragma unroll
        for (int i = 0; i < 4; i++) {
            int q4 = 4 * lane + i;
            gbp[wid][q4 >> 5][q4 & 31] = gw[i];
        }
    }

    int m = lane & 31, h2 = lane >> 5;
    if (lane < 32) nbb[wid][lane] = neighbors[n * 32 + lane];
    float tm = times[n * 32 + m];
    bool valid = (tm <= t0);
    unsigned long long bal = __ballot(valid);
    bool anyv = (bal != 0ull);

    // ---- V preload ----
    u32 vpre[32];
    #pragma unroll
    for (int mm = 0; mm < 32; mm++) {
        int nbm = nbb[wid][mm];
        vpre[mm] = *(const u32*)(Vb + (size_t)nbm * 128 + 2 * lane);
    }

    // ---- time encoding (hw-sin: fma + fract + v_sin per element) ----
    int kbase = 32 * h2;
    #pragma unroll
    for (int i = 0; i < 16; i++) {
        int k0 = kbase + 2 * i;
        float2 wbA = wb2p[k0];
        float2 wbB = wb2p[k0 + 1];
        float yA = fmaf(tm, wbA.x, wbA.y);
        float yB = fmaf(tm, wbB.x, wbB.y);
        float v0 = (k0 == 0) ? yA : hwsin(yA);
        float v1 = hwsin(yB);
        *(u32*)&enc[wid][m][k0] = pk2(v0, v1);
    }

    // cb_[h] = q_h . btk_h
    if (lane < 8) {
        float s = 0.f;
        #pragma unroll
        for (int j = 0; j < 8; j++) {
            u32 qp = qb[wid][lane * 8 + j];
            s += bfl(qp) * btk[lane * 16 + 2 * j] + bfh(qp) * btk[lane * 16 + 2 * j + 1];
        }
        cb_[wid][lane] = s;
    }

    // ================= scores via MFMA =================
    f32x4 accS[2];
    accS[0] = (f32x4){0.f, 0.f, 0.f, 0.f};
    accS[1] = (f32x4){0.f, 0.f, 0.f, 0.f};

    int nb0 = nbb[wid][l15];
    int nb1 = nbb[wid][l15 + 16];
    const u16* K0 = Kb + (size_t)nb0 * 128;
    const u16* K1 = Kb + (size_t)nb1 * 128;
    const int4 zero4 = {0, 0, 0, 0};
    #pragma unroll
    for (int ks = 0; ks < 4; ks++) {
        bf16x8 qf = bcast8((l15 == ks * 2 + (lg >> 1))
                               ? *(const int4*)&qb[wid][ks * 16 + lg * 4]
                               : zero4);
        bf16x8 k0f = bcast8(*(const int4*)(K0 + ks * 32 + lg * 8));
        bf16x8 k1f = bcast8(*(const int4*)(K1 + ks * 32 + lg * 8));
        accS[0] = __builtin_amdgcn_mfma_f32_16x16x32_bf16(k0f, qf, accS[0], 0, 0, 0);
        accS[1] = __builtin_amdgcn_mfma_f32_16x16x32_bf16(k1f, qf, accS[1], 0, 0, 0);
    }
    #pragma unroll
    for (int ks = 0; ks < 2; ks++) {
        int4 gi = zero4;
        if (l15 < 8) {
            int2 ga = *(const int2*)&gbp[wid][l15][ks * 16 + lg * 4];
            int2 gbq = *(const int2*)&gbp[wid][l15][ks * 16 + lg * 4 + 2];
            gi.x = ga.x; gi.y = ga.y; gi.z = gbq.x; gi.w = gbq.y;
        }
        bf16x8 gf = bcast8(gi);
        bf16x8 e0 = *(const bf16x8*)&enc[wid][l15][ks * 32 + lg * 8];
        bf16x8 e1 = *(const bf16x8*)&enc[wid][l15 + 16][ks * 32 + lg * 8];
        accS[0] = __builtin_amdgcn_mfma_f32_16x16x32_bf16(e0, gf, accS[0], 0, 0, 0);
        accS[1] = __builtin_amdgcn_mfma_f32_16x16x32_bf16(e1, gf, accS[1], 0, 0, 0);
    }

    // ---- finalize + softmax (mask from ballot) ----
    float cbv = (l15 < 8) ? cb_[wid][l15] : 0.f;
    float sc[2][4];
    #pragma unroll
    for (int mt = 0; mt < 2; mt++) {
        #pragma unroll
        for (int j = 0; j < 4; j++) {
            int mr = mt * 16 + lg * 4 + j;
            float v = 0.25f * (accS[mt][j] + cbv);
            sc[mt][j] = ((bal >> mr) & 1ull) ? v : -1e9f;
        }
    }
    float mx = sc[0][0];
    #pragma unroll
    for (int mt = 0; mt < 2; mt++)
        #pragma unroll
        for (int j = 0; j < 4; j++) mx = fmaxf(mx, sc[mt][j]);
    mx = fmaxf(mx, __shfl_xor(mx, 16));
    mx = fmaxf(mx, __shfl_xor(mx, 32));
    float p[2][4];
    float s = 0.f;
    #pragma unroll
    for (int mt = 0; mt < 2; mt++)
        #pragma unroll
        for (int j = 0; j < 4; j++) { p[mt][j] = __expf(sc[mt][j] - mx); s += p[mt][j]; }
    s += __shfl_xor(s, 16);
    s += __shfl_xor(s, 32);
    float inv = 1.0f / s;
    if (l15 < 8) {
        #pragma unroll
        for (int mt = 0; mt < 2; mt++)
            #pragma unroll
            for (int j = 0; j < 4; j++)
                pbuf[wid][l15][mt * 16 + lg * 4 + j] = p[mt][j] * inv;
    }

    // ================= ewp = P^T @ enc via MFMA =================
    {
        int hh = l15 & 7;
        float pa[8];
        #pragma unroll
        for (int j = 0; j < 8; j++) pa[j] = pbuf[wid][hh][8 * lg + j];
        int4 ai;
        ai.x = pk2(pa[0], pa[1]); ai.y = pk2(pa[2], pa[3]);
        ai.z = pk2(pa[4], pa[5]); ai.w = pk2(pa[6], pa[7]);
        bf16x8 af = bcast8(ai);
        #pragma unroll
        for (int nt = 0; nt < 4; nt++) {
            int col = nt * 16 + l15;
            int4 bi;
            bi.x = (u32)enc[wid][8 * lg + 0][col] | ((u32)enc[wid][8 * lg + 1][col] << 16);
            bi.y = (u32)enc[wid][8 * lg + 2][col] | ((u32)enc[wid][8 * lg + 3][col] << 16);
            bi.z = (u32)enc[wid][8 * lg + 4][col] | ((u32)enc[wid][8 * lg + 5][col] << 16);
            bi.w = (u32)enc[wid][8 * lg + 6][col] | ((u32)enc[wid][8 * lg + 7][col] << 16);
            bf16x8 bfr = bcast8(bi);
            f32x4 ce = (f32x4){0.f, 0.f, 0.f, 0.f};
            ce = __builtin_amdgcn_mfma_f32_16x16x32_bf16(af, bfr, ce, 0, 0, 0);
            if (lg < 2) {
                #pragma unroll
                for (int j = 0; j < 4; j++)
                    ewp[wid][4 * lg + j][col] = f2b(ce[j]);
            }
        }
    }

    // ---- V aggregation (VALU) ----
    int myh = lane >> 3;
    float av0 = 0.f, av1 = 0.f;
    #pragma unroll
    for (int mm = 0; mm < 32; mm++) {
        float a = pbuf[wid][myh][mm];
        av0 += a * bfl(vpre[mm]);
        av1 += a * bfh(vpre[mm]);
    }
    // ---- time-value term ----
    float ht0 = 0.f, ht1 = 0.f;
    #pragma unroll 8
    for (int kp = 0; kp < 32; kp++) {
        u32 ew = *(const u32*)&ewp[wid][myh][2 * kp];
        int2 wv = *(const int2*)&Wtvp[kp * 128 + 2 * lane];
        ht0 = dot2b(ew, (u32)wv.x, ht0);
        ht1 = dot2b(ew, (u32)wv.y, ht1);
    }
    float2 bt2 = *(const float2*)&btv[2 * lane];
    float ox = anyv ? (av0 + ht0 + bt2.x) : 0.0f;
    float oy = anyv ? (av1 + ht1 + bt2.y) : 0.0f;
    ((u32*)Hb)[(size_t)n * 64 + lane] = pk2(ox, oy);
}

// ---------------------------------------------------------------------------
extern "C" void kernel_launch(void* const* d_in, const int* in_sizes, int n_in,
                              void* d_out, int out_size, void* d_ws, size_t ws_size,
                              hipStream_t stream)
{
    const float* x        = (const float*)d_in[0];
    const int*   neighbors= (const int*)  d_in[1];
    const float* times    = (const float*)d_in[2];
    const float* t        = (const float*)d_in[3];
    const float* Wk  = (const float*)d_in[4];
    const float* bk  = (const float*)d_in[5];
    const float* Wq  = (const float*)d_in[6];
    const float* bq  = (const float*)d_in[7];
    const float* Wv  = (const float*)d_in[8];
    const float* bv  = (const float*)d_in[9];
    const float* w0  = (const float*)d_in[10];
    const float* b0  = (const float*)d_in[11];
    const float* Wt  = (const float*)d_in[12];
    const float* Bt  = (const float*)d_in[13];
    const float* Wtk = (const float*)d_in[14];
    const float* btk = (const float*)d_in[15];
    const float* Wtq = (const float*)d_in[16];
    const float* btq = (const float*)d_in[17];
    const float* Wtv = (const float*)d_in[18];
    const float* btv = (const float*)d_in[19];
    const float* W1  = (const float*)d_in[20];
    const float* b1  = (const float*)d_in[21];
    const float* W2  = (const float*)d_in[22];
    const float* b2  = (const float*)d_in[23];

    float* ws = (float*)d_ws;
    const size_t NF = (size_t)NNODES * 128;
    u16*   Kb    = (u16*)ws;                             // NF bf16
    u16*   Qb    = Kb + NF;                              // NF bf16
    u16*   Vb    = Qb + NF;                              // NF bf16
    u16*   Pb    = Vb + NF;                              // NF bf16
    u16*   Hb    = Pb + NF;                              // NF bf16
    u16*   Gb    = Hb + NF;                              // N*512 bf16
    float* qbias = (float*)(Gb + (size_t)NNODES * 512);  // 128 f32
    u16*   Wts   = (u16*)(qbias + 128);                  // 6*16384 bf16
    u16*   WGt   = Wts + 6 * 16384;                      // 65536 bf16
    float* gb    = (float*)(WGt + 65536);                // 512 f32
    u32*   Wtvp  = (u32*)(gb + 512);                     // 4096 u32
    float2* wb2p = (float2*)(Wtvp + 4096);               // 64 float2

    setup_all<<<107, 256, 0, stream>>>(Wk, Wq, Wv, W1, W2,
                                       t, bq, btq, Wtq, w0, b0, Wt, Bt,
                                       Wtk, Wtv,
                                       Wts, qbias, gb, Wtvp, WGt, wb2p);

    gemm8m4<<<dim3(NNODES / 64, 2), 256, 0, stream>>>(
        x, Wts, WGt, bk, qbias, bv, b1, gb, Kb, Qb, Vb, Pb, Gb);

    attn_kernel<<<NNODES / 4, 256, 0, stream>>>(neighbors, times, t,
                                                Kb, Qb, Vb, Gb,
                                                btk, Wtvp, btv, wb2p,
                                                Hb);

    mlp_fused<<<NNODES / 32, 256, 0, stream>>>(Hb, Wts, Pb, b2,
                                               (float*)d_out);
}